// Round 19
// baseline (131.380 us; speedup 1.0000x reference)
//
#include <hip/hip_runtime.h>

typedef _Float16 f16;
typedef _Float16 f16x8 __attribute__((ext_vector_type(8)));
typedef _Float16 f16x4 __attribute__((ext_vector_type(4)));
typedef float    f32x4 __attribute__((ext_vector_type(4)));

#define MFMA16(a, b, c) __builtin_amdgcn_mfma_f32_16x16x32_f16((a), (b), (c), 0, 0, 0)

// async global->LDS, 16B per lane; LDS dest is wave-uniform base + lane*16
__device__ __forceinline__ void gload16(const void* g, void* l) {
  __builtin_amdgcn_global_load_lds(
      (const __attribute__((address_space(1))) unsigned int*)g,
      (__attribute__((address_space(3))) unsigned int*)l, 16, 0, 0);
}

// raw v_exp_f32: computes 2^x (scores are kept in log2 domain)
__device__ __forceinline__ float ex2(float x) {
  float r;
  asm("v_exp_f32 %0, %1" : "=v"(r) : "v"(x));
  return r;
}

// counted-vmcnt wait: N loads may stay outstanding (T4). "memory" clobber
// fences the compiler so LDS reads/stage issues don't cross it.
#define WAITV(N) asm volatile("s_waitcnt vmcnt(" #N ")" ::: "memory")
#define BARRIER() __builtin_amdgcn_s_barrier()
#define CFENCE() asm volatile("" ::: "memory")

// ---------------- prep kernel: weight transposes only ----------------
// grid 4096: bx2 = bx&127, by = bx>>7; bx2 < 96 -> w_qkv (1024x3072),
// else w_out (1024x1024). out[c][r] = (f16) in[r][c].
__global__ void prep(const float* __restrict__ wqkv, f16* __restrict__ oqkv,
                     const float* __restrict__ wout, f16* __restrict__ oout) {
  __shared__ float tile[32][33];
  int bx = blockIdx.x, t = threadIdx.x;
  int bx2 = bx & 127, by = bx >> 7;
  const float* in;
  f16* out;
  int Cc, c0;
  if (bx2 < 96) { in = wqkv; out = oqkv; Cc = 3072; c0 = bx2 * 32; }
  else          { in = wout; out = oout; Cc = 1024; c0 = (bx2 - 96) * 32; }
  int r0 = by * 32;
  int tx = t & 31, ty = t >> 5;
#pragma unroll
  for (int i = ty; i < 32; i += 8)
    tile[i][tx] = in[(size_t)(r0 + i) * Cc + c0 + tx];
  __syncthreads();
#pragma unroll
  for (int i = ty; i < 32; i += 8)
    out[(size_t)(c0 + i) * 1024 + r0 + tx] = (f16)tile[tx][i];
}

// ---------------- GEMM core 64x128 (R13/R18-verified) ----------------
// C[64x128] = A[bm*64.., K] * Bt[bn*128.., K]^T. 4 waves: wm = wave>>1 (32 rows),
// wn = wave&1 (64 cols); acc[2][4]. LDS 24KB -> 2+ blocks/CU.
template <int KDIM>
__device__ __forceinline__ void gemm_core64(const f16* __restrict__ A, const f16* __restrict__ Bt,
                                            int bm, int bn, f16* lA, f16* lB, f32x4 acc[2][4]) {
  const int t = threadIdx.x, lane = t & 63, wave = t >> 6;
  const int wm = wave >> 1, wn = wave & 1;
  const int srow = lane >> 3;            // row within 8-row chunk
  const int skb = (lane & 7) * 16;       // byte offset within 128B row
  const int nkt = KDIM / 64;
  for (int kt = 0; kt < nkt; ++kt) {
    __syncthreads();
#pragma unroll
    for (int c = 0; c < 2; ++c) {        // A: 8 chunks of 8 rows
      int cc = c * 4 + wave;             // 0..7
      int row = cc * 8 + srow;           // 0..63
      int kbs = skb ^ ((row & 7) << 4);
      gload16((const char*)A + (size_t)(bm * 64 + row) * (KDIM * 2) + kt * 128 + kbs,
              lA + cc * 512);
    }
#pragma unroll
    for (int c = 0; c < 4; ++c) {        // B: 16 chunks of 8 rows
      int cc = c * 4 + wave;             // 0..15
      int row = cc * 8 + srow;           // 0..127
      int kbs = skb ^ ((row & 7) << 4);
      gload16((const char*)Bt + (size_t)(bn * 128 + row) * (KDIM * 2) + kt * 128 + kbs,
              lB + cc * 512);
    }
    __syncthreads();
#pragma unroll
    for (int ks = 0; ks < 2; ++ks) {
      f16x8 af[2], bf[4];
#pragma unroll
      for (int mi = 0; mi < 2; ++mi) {
        int r = wm * 32 + mi * 16 + (lane & 15);
        int ke = (ks * 32 + ((lane >> 4) << 3)) ^ ((r & 7) << 3);
        af[mi] = *(const f16x8*)&lA[r * 64 + ke];
      }
#pragma unroll
      for (int ni = 0; ni < 4; ++ni) {
        int r = wn * 64 + ni * 16 + (lane & 15);
        int ke = (ks * 32 + ((lane >> 4) << 3)) ^ ((r & 7) << 3);
        bf[ni] = *(const f16x8*)&lB[r * 64 + ke];
      }
#pragma unroll
      for (int mi = 0; mi < 2; ++mi)
#pragma unroll
        for (int ni = 0; ni < 4; ++ni)
          acc[mi][ni] = MFMA16(af[mi], bf[ni], acc[mi][ni]);
    }
  }
}

// ---------------- QKV projection: A = x read as RAW F32, reg-staged ----------------
// A-stage: each thread loads 8 float4 of x (row = t>>1, half = t&1), converts,
// and ds_write_b128's into the PROVEN f16 [128][64] swizzled layout
// (content ^((row&7)<<3) elems) — read path identical to R10/R18. B staged via
// global_load_lds as before. Kills the separate cast kernel + xh round trip.
// sec0 -> Q*0.125*log2(e); sec1 -> K; sec2 -> V^T[B,H,D,N] key-permuted within
// 32-blocks (PV lane-locality), via LDS transpose -> f16x8 coalesced stores.
// Grid: 1D 768, XCD-chunked: XCD (w&7) owns an 8bm x 12bn tile chunk.
__global__ __launch_bounds__(256, 2) void gemm_qkv(const float* __restrict__ X,
                                                   const f16* __restrict__ Bt,
                                                   f16* __restrict__ Qo, f16* __restrict__ Ko,
                                                   f16* __restrict__ Vt) {
  __shared__ __align__(16) f16 smem[128 * 136];  // 34816 B; staging uses first 32KB
  f16* lA = smem;
  f16* lB = smem + 8192;
  f32x4 acc[4][4] = {};
  int w = blockIdx.x;            // 0..767
  int xcd = w & 7, i = w >> 3;   // i in [0,96)
  int xr = xcd >> 1, xc = xcd & 1;
  int bm = xr * 8 + (i & 7);     // [0,32)
  int bn = xc * 12 + (i >> 3);   // [0,24)
  const int t = threadIdx.x, lane = t & 63, wave = t >> 6;
  const int wm = wave >> 1, wn = wave & 1;
  const int g = lane >> 4, q15 = lane & 15;
  {
    const int srowB = lane >> 3, skbB = (lane & 7) * 16;
    const int arow = t >> 1, ahalf = t & 1;          // A: row 0..127, 32-f32 half
    const float* asrc_base = X + (size_t)(bm * 128 + arow) * 1024 + ahalf * 32;
    const int aswz = (arow & 7) << 3;                // element swizzle
    for (int kt = 0; kt < 16; ++kt) {
      __syncthreads();  // previous MFMA phase's LDS reads complete
      // A: 8x float4 f32 loads (registers)
      float4 a4[8];
      const float4* asrc = (const float4*)(asrc_base + kt * 64);
#pragma unroll
      for (int j = 0; j < 8; ++j) a4[j] = asrc[j];
      // B: global_load_lds staging (unchanged)
#pragma unroll
      for (int c = 0; c < 4; ++c) {
        int cc = c * 4 + wave;             // 0..15
        int row = cc * 8 + srowB;          // 0..127
        int kbs = skbB ^ ((row & 7) << 4);
        gload16((const char*)Bt + (size_t)(bn * 128 + row) * 2048 + kt * 128 + kbs,
                lB + cc * 512);
      }
      // A: convert + swizzled ds_write (content layout identical to f16 path)
#pragma unroll
      for (int qd = 0; qd < 4; ++qd) {
        f16x8 wv;
#pragma unroll
        for (int e = 0; e < 4; ++e) {
          wv[e] = (f16)a4[qd * 2][e];
          wv[4 + e] = (f16)a4[qd * 2 + 1][e];
        }
        *(f16x8*)&lA[arow * 64 + ((ahalf * 32 + qd * 8) ^ aswz)] = wv;
      }
      __syncthreads();  // drains vm (B DMA) + lgkm (A writes) before reads
#pragma unroll
      for (int ks = 0; ks < 2; ++ks) {
        f16x8 af[4], bf[4];
#pragma unroll
        for (int mi = 0; mi < 4; ++mi) {
          int r = wm * 64 + mi * 16 + q15;
          int ke = (ks * 32 + (g << 3)) ^ ((r & 7) << 3);
          af[mi] = *(const f16x8*)&lA[r * 64 + ke];
        }
#pragma unroll
        for (int ni = 0; ni < 4; ++ni) {
          int r = wn * 64 + ni * 16 + q15;
          int ke = (ks * 32 + (g << 3)) ^ ((r & 7) << 3);
          bf[ni] = *(const f16x8*)&lB[r * 64 + ke];
        }
#pragma unroll
        for (int mi = 0; mi < 4; ++mi)
#pragma unroll
          for (int ni = 0; ni < 4; ++ni)
            acc[mi][ni] = MFMA16(af[mi], bf[ni], acc[mi][ni]);
      }
    }
  }
  int sec = (bn * 128) >> 10;  // 0=Q 1=K 2=V, uniform per block (128 | 1024)
  if (sec < 2) {
    float scl = (sec == 0) ? 0.18033688f : 1.0f;  // 0.125 * log2(e)
#pragma unroll
    for (int mi = 0; mi < 4; ++mi)
#pragma unroll
      for (int ni = 0; ni < 4; ++ni)
#pragma unroll
        for (int reg = 0; reg < 4; ++reg) {
          int gr = bm * 128 + wm * 64 + mi * 16 + (g << 2) + reg;  // [0,4096)
          int gc = bn * 128 + wn * 64 + ni * 16 + q15;             // [0,3072)
          int b = gr >> 11, n = gr & 2047;
          int jj = gc & 1023;
          int h = jj >> 6, d = jj & 63;
          f16 v = (f16)(acc[mi][ni][reg] * scl);
          size_t bh = (size_t)(b * 16 + h);
          if (sec == 0) Qo[(bh * 2048 + n) * 64 + d] = v;
          else          Ko[(bh * 2048 + n) * 64 + d] = v;
        }
  } else {
    // V: acc(rl = n, cl = head*64+d) -> LDS[cl][p(rl)] -> coalesced V^T
    __syncthreads();  // all LDS reads of the K-loop complete before overwrite
#pragma unroll
    for (int mi = 0; mi < 4; ++mi)
#pragma unroll
      for (int ni = 0; ni < 4; ++ni)
#pragma unroll
        for (int reg = 0; reg < 4; ++reg) {
          int rl = wm * 64 + mi * 16 + (g << 2) + reg;  // local n 0..127
          int cl = wn * 64 + ni * 16 + q15;             // local col 0..127
          int r5 = rl & 31;
          int rlp = (rl & ~31) | (((r5 >> 2) & 3) << 3) | (((r5 >> 4) & 1) << 2) | (r5 & 3);
          smem[cl * 136 + rlp] = (f16)acc[mi][ni][reg];
        }
    __syncthreads();
    int tid = threadIdx.x;
    int cl = tid >> 1, half = tid & 1;
    int jj = (bn * 128 + cl) & 1023;
    int h = jj >> 6, d = jj & 63;
    int b = (bm * 128) >> 11;
    size_t bh = (size_t)(b * 16 + h);
    f16* dst = Vt + (bh * 64 + d) * 2048 + (bm * 128 & 2047) + half * 64;
    const f16* src = smem + cl * 136 + half * 64;
#pragma unroll
    for (int j8 = 0; j8 < 8; ++j8)
      *(f16x8*)&dst[j8 * 8] = *(const f16x8*)&src[j8 * 8];
  }
}

// ---------------- causal flash attention (R11-best: 64-key, 4 blocks/CU) ----------------
// Q pre-scaled by 0.125*log2e (log2-domain scores). Q,K: [B,H,N,D] f16;
// Vt: [B,H,D,N] f16 (key-permuted); Ob: [N,C] slice.
// 64-key tiles, double-buffered with counted vmcnt (T4): 2 stages (4 loads each)
// in flight; WAITV(4) retires the stage being consumed while the newer 4 loads
// stay in flight across both barriers. K LDS [64][64], V LDS [64][64], row-swizzled.
// Swapped-operand: S^T = mfma(K, Q); q = lane&15, k = kv0 + 16*ni + 4*(lane>>4) + reg.
__device__ __forceinline__ void attn_one(const f16* __restrict__ Qb, const f16* __restrict__ Kb,
                                         const f16* __restrict__ Vb, f16* __restrict__ Ob,
                                         int qt, int lane, int wave, f16* lK, f16* lV) {
  const int N = 2048;
  const int wq0 = qt * 64 + wave * 16;
  const int g = lane >> 4, q15 = lane & 15;
  f16x8 qf[2];
#pragma unroll
  for (int ks = 0; ks < 2; ++ks)
    qf[ks] = *(const f16x8*)&Qb[(size_t)(wq0 + q15) * 64 + ks * 32 + (g << 3)];
  f32x4 oacc[4] = {};
  float mrun = -1e30f, lrun = 0.f;
  const int srow = lane >> 3, skb = (lane & 7) * 16;
  const int ntiles = qt + 1;  // 64-key tiles

  auto STAGE = [&](int buf, int kv) {  // 4 gload16 per wave
    int kv0 = kv << 6;
#pragma unroll
    for (int c = 0; c < 2; ++c) {
      int cc = c * 4 + wave;             // 0..7, wave-uniform
      int row = cc * 8 + srow;           // 0..63
      int kbs = skb ^ ((row & 7) << 4);  // pre-swizzled source
      gload16((const char*)Kb + (size_t)(kv0 + row) * 128 + kbs, lK + buf * 4096 + cc * 512);
      gload16((const char*)Vb + (size_t)row * (N * 2) + (size_t)kv0 * 2 + kbs,
              lV + buf * 4096 + cc * 512);
    }
  };

  STAGE(0, 0);
  if (ntiles > 1) STAGE(1, 1);
  for (int kv = 0; kv < ntiles; ++kv) {
    int cur = kv & 1;
    if (kv + 1 < ntiles) WAITV(4); else WAITV(0);
    BARRIER();  // buf cur complete in all waves
    const f16* K0 = lK + cur * 4096;
    const f16* V0 = lV + cur * 4096;
    int kv0 = kv << 6;
    f32x4 s[4] = {};
    __builtin_amdgcn_s_setprio(1);
#pragma unroll
    for (int ks = 0; ks < 2; ++ks) {
      f16x8 kf[4];
#pragma unroll
      for (int ni = 0; ni < 4; ++ni) {
        int r = ni * 16 + q15;                       // key row 0..63
        int ke = (ks * 32 + (g << 3)) ^ ((r & 7) << 3);
        kf[ni] = *(const f16x8*)&K0[r * 64 + ke];
      }
#pragma unroll
      for (int ni = 0; ni < 4; ++ni) s[ni] = MFMA16(kf[ni], qf[ks], s[ni]);  // S^T[k][q]
    }
    __builtin_amdgcn_s_setprio(0);
    if (kv == qt) {  // diagonal tile: causal mask. k = kv0+16ni+4g+reg, q = wq0+q15.
      int gq = wq0 + q15;
#pragma unroll
      for (int ni = 0; ni < 4; ++ni)
#pragma unroll
        for (int reg = 0; reg < 4; ++reg) {
          int gk = kv0 + ni * 16 + g * 4 + reg;
          if (gk > gq) s[ni][reg] = -1e30f;
        }
    }
    // per-lane max over 16 regs + 2 shfl (lanes l, l+16, l+32, l+48 share q)
    f32x4 m4 = s[0];
#pragma unroll
    for (int ni = 1; ni < 4; ++ni)
#pragma unroll
      for (int reg = 0; reg < 4; ++reg) m4[reg] = fmaxf(m4[reg], s[ni][reg]);
    float mx = fmaxf(fmaxf(m4[0], m4[1]), fmaxf(m4[2], m4[3]));
    mx = fmaxf(mx, __shfl_xor(mx, 16));
    mx = fmaxf(mx, __shfl_xor(mx, 32));
    // T13: rescale only if some row's running max grew (wave-uniform)
    if (__any(mx > mrun)) {
      float mnew = fmaxf(mrun, mx);
      float corr = ex2(mrun - mnew);
      mrun = mnew;
      lrun *= corr;
#pragma unroll
      for (int ni = 0; ni < 4; ++ni)
#pragma unroll
        for (int reg = 0; reg < 4; ++reg) oacc[ni][reg] *= corr;
    }
    // p = 2^(s-m); tree-shaped row-sum (4 parallel f32x4 chains + horizontal)
#pragma unroll
    for (int ni = 0; ni < 4; ++ni)
#pragma unroll
      for (int reg = 0; reg < 4; ++reg) s[ni][reg] = ex2(s[ni][reg] - mrun);
    f32x4 racc = (s[0] + s[1]) + (s[2] + s[3]);
    float rsum = (racc[0] + racc[1]) + (racc[2] + racc[3]);
    rsum += __shfl_xor(rsum, 16);
    rsum += __shfl_xor(rsum, 32);
    lrun += rsum;
    // pack P fragments (lane-local; order matches permuted V layout)
    f16x8 pf[2];
#pragma unroll
    for (int ks = 0; ks < 2; ++ks)
#pragma unroll
      for (int e = 0; e < 8; ++e) pf[ks][e] = (f16)s[2 * ks + (e >> 2)][e & 3];
    // O^T[d][q] += V^T_perm @ P  (A = V rows d from LDS, B = pf in-register)
    __builtin_amdgcn_s_setprio(1);
#pragma unroll
    for (int ks = 0; ks < 2; ++ks) {
      f16x8 vf[4];
#pragma unroll
      for (int mi = 0; mi < 4; ++mi) {
        int r = mi * 16 + q15;                       // d row 0..63
        int ke = (ks * 32 + (g << 3)) ^ ((r & 7) << 3);
        vf[mi] = *(const f16x8*)&V0[r * 64 + ke];
      }
#pragma unroll
      for (int mi = 0; mi < 4; ++mi) oacc[mi] = MFMA16(vf[mi], pf[ks], oacc[mi]);
    }
    __builtin_amdgcn_s_setprio(0);
    BARRIER();  // all waves done reading cur
    CFENCE();
    if (kv + 2 < ntiles) STAGE(cur, kv + 2);
  }
  // epilogue: O^T[d][q] -> Ob[q, d]; d = 16*mi + 4*g + reg (4 contiguous per mi)
  float inv = 1.0f / lrun;
  int gq = wq0 + q15;
#pragma unroll
  for (int mi = 0; mi < 4; ++mi) {
    f16x4 o4;
#pragma unroll
    for (int reg = 0; reg < 4; ++reg) o4[reg] = (f16)(oacc[mi][reg] * inv);
    *(f16x4*)&Ob[(size_t)gq * 1024 + mi * 16 + g * 4] = o4;
  }
}

// 1024 blocks, one 64-row q-tile each -> 4 blocks/CU.
// XCD-chunked (T1): XCD c = w&7 owns heads [4c,4c+4) -> 2 MB K/V set per XCD L2.
// Sum-uniform placement: within a chunk, j = 32a + k; under breadth-first
// dispatch CU k receives a=0..3 with qt {k, 31-k, (k+8)&31, 31-((k+8)&31)}
// -> per-CU work sums to exactly 66 tile-units for every k.
__global__ __launch_bounds__(256, 4) void attn(const f16* __restrict__ Q,
                                               const f16* __restrict__ K,
                                               const f16* __restrict__ Vt,
                                               f16* __restrict__ O) {
  __shared__ __align__(16) f16 lK[2 * 4096];
  __shared__ __align__(16) f16 lV[2 * 4096];
  int w = blockIdx.x;             // 0..1023
  int c = w & 7, j = w >> 3;      // XCD chunk id, index within chunk [0,128)
  int a = j >> 5, k = j & 31;     // head-slot, CU-slot
  int bh = c * 4 + a;
  int kk = (a >= 2) ? ((k + 8) & 31) : k;
  int qt = (a & 1) ? (31 - kk) : kk;
  int b = bh >> 4, h = bh & 15;
  int lane = threadIdx.x & 63, wave = threadIdx.x >> 6;
  const f16* Qb = Q + (size_t)bh * 2048 * 64;
  const f16* Kb = K + (size_t)bh * 2048 * 64;
  const f16* Vb = Vt + (size_t)bh * 2048 * 64;
  f16* Ob = O + (size_t)b * 2048 * 1024 + h * 64;
  attn_one(Qb, Kb, Vb, Ob, qt, lane, wave, lK, lV);
}

// ---------------- output projection: 64x128 tiles, 512 blocks (2/CU) ----------------
// XCD-chunked: XCD (w&7) owns 8bm x 8bn.
__global__ __launch_bounds__(256, 2) void gemm_out(const f16* __restrict__ A,
                                                   const f16* __restrict__ Bt,
                                                   const float* __restrict__ bias,
                                                   float* __restrict__ out) {
  __shared__ __align__(16) f16 smem[12288];  // 24KB: lA 8KB + lB 16KB
  f16* lA = smem;
  f16* lB = smem + 4096;
  f32x4 acc[2][4] = {};
  int w = blockIdx.x;           // 0..511
  int xcd = w & 7, i = w >> 3;  // [0,64)
  int bm = xcd * 8 + (i & 7);   // [0,64)
  int bn = i >> 3;              // [0,8)
  gemm_core64<1024>(A, Bt, bm, bn, lA, lB, acc);
  int lane = threadIdx.x & 63, wave = threadIdx.x >> 6;
  int wm = wave >> 1, wn = wave & 1;
#pragma unroll
  for (int mi = 0; mi < 2; ++mi)
#pragma unroll
    for (int ni = 0; ni < 4; ++ni)
#pragma unroll
      for (int reg = 0; reg < 4; ++reg) {
        int gr = bm * 64 + wm * 32 + mi * 16 + ((lane >> 4) << 2) + reg;
        int gc = bn * 128 + wn * 64 + ni * 16 + (lane & 15);
        out[(size_t)gr * 1024 + gc] = acc[mi][ni][reg] + bias[gc];
      }
}

// ---------------- launcher ----------------
extern "C" void kernel_launch(void* const* d_in, const int* in_sizes, int n_in,
                              void* d_out, int out_size, void* d_ws, size_t ws_size,
                              hipStream_t stream) {
  const float* x     = (const float*)d_in[0];  // [2,2048,1024]
  const float* w_qkv = (const float*)d_in[1];  // [1024,3072]
  const float* w_out = (const float*)d_in[2];  // [1024,1024]
  const float* b_out = (const float*)d_in[3];  // [1024]
  // d_in[4] = attn_mask (causal; computed analytically)
  float* out = (float*)d_out;
  char* ws = (char*)d_ws;

  f16* wqkvT = (f16*)(ws + (8u << 20));      //  6 MB [3072,1024]
  f16* woutT = (f16*)(ws + (14u << 20));     //  2 MB [1024,1024]
  f16* Qs    = (f16*)(ws + (16u << 20));     //  8 MB [B,H,N,D] (pre-scaled, log2-domain)
  f16* Ks    = (f16*)(ws + (24u << 20));     //  8 MB [B,H,N,D]
  f16* Vts   = (f16*)(ws + (32u << 20));     //  8 MB [B,H,D,N] (key-permuted)
  f16* Oa    = (f16*)(ws + (40u << 20));     //  8 MB [B,N,H*D]

  prep<<<4096, 256, 0, stream>>>(w_qkv, wqkvT, w_out, woutT);
  gemm_qkv<<<768, 256, 0, stream>>>(x, wqkvT, Qs, Ks, Vts);
  attn<<<1024, 256, 0, stream>>>(Qs, Ks, Vts, Oa);
  gemm_out<<<512, 256, 0, stream>>>(Oa, woutT, b_out, out);
}

// Round 20
// 100.767 us; speedup vs baseline: 1.3038x; 1.3038x over previous
//
#include <hip/hip_runtime.h>

typedef _Float16 f16;
typedef _Float16 f16x8 __attribute__((ext_vector_type(8)));
typedef _Float16 f16x4 __attribute__((ext_vector_type(4)));
typedef float    f32x4 __attribute__((ext_vector_type(4)));

#define MFMA16(a, b, c) __builtin_amdgcn_mfma_f32_16x16x32_f16((a), (b), (c), 0, 0, 0)

// async global->LDS, 16B per lane; LDS dest is wave-uniform base + lane*16
__device__ __forceinline__ void gload16(const void* g, void* l) {
  __builtin_amdgcn_global_load_lds(
      (const __attribute__((address_space(1))) unsigned int*)g,
      (__attribute__((address_space(3))) unsigned int*)l, 16, 0, 0);
}

// raw v_exp_f32: computes 2^x (scores are kept in log2 domain)
__device__ __forceinline__ float ex2(float x) {
  float r;
  asm("v_exp_f32 %0, %1" : "=v"(r) : "v"(x));
  return r;
}

// counted-vmcnt wait: N loads may stay outstanding (T4). "memory" clobber
// fences the compiler so LDS reads/stage issues don't cross it.
#define WAITV(N) asm volatile("s_waitcnt vmcnt(" #N ")" ::: "memory")
#define BARRIER() __builtin_amdgcn_s_barrier()
#define CFENCE() asm volatile("" ::: "memory")

// ---------------- merged prep kernel ----------------
// bx < 4096: cast x f32 -> f16 (float4 per thread).
// else: weight transpose tiles; tb = bx-4096, bx2 = tb&127, by = tb>>7;
//       bx2 < 96 -> w_qkv (1024x3072), else w_out (1024x1024).
__global__ void prep(const float* __restrict__ x, f16* __restrict__ xh,
                     const float* __restrict__ wqkv, f16* __restrict__ oqkv,
                     const float* __restrict__ wout, f16* __restrict__ oout) {
  __shared__ float tile[32][33];
  int bx = blockIdx.x, t = threadIdx.x;
  if (bx < 4096) {
    int i = bx * 256 + t;
    float4 v = ((const float4*)x)[i];
    f16x4 o;
    o.x = (f16)v.x; o.y = (f16)v.y; o.z = (f16)v.z; o.w = (f16)v.w;
    ((f16x4*)xh)[i] = o;
    return;
  }
  int tb = bx - 4096;
  int bx2 = tb & 127, by = tb >> 7;
  const float* in;
  f16* out;
  int Cc, c0;
  if (bx2 < 96) { in = wqkv; out = oqkv; Cc = 3072; c0 = bx2 * 32; }
  else          { in = wout; out = oout; Cc = 1024; c0 = (bx2 - 96) * 32; }
  int r0 = by * 32;
  int tx = t & 31, ty = t >> 5;
#pragma unroll
  for (int i = ty; i < 32; i += 8)
    tile[i][tx] = in[(size_t)(r0 + i) * Cc + c0 + tx];
  __syncthreads();
#pragma unroll
  for (int i = ty; i < 32; i += 8)
    out[(size_t)(c0 + i) * 1024 + r0 + tx] = (f16)tile[tx][i];
}

// ---------------- GEMM core 128x128 (R6/R10-proven: single 32KB buffer, BK=64) ----------------
// C[128x128] tile = A[bm*128.., K] * Bt[bn*128.., K]^T, K = KDIM, fp16 in, f32 acc.
// LDS layout: [row][64] f16, content swizzled: LDS(row, kb) = global(row, kb ^ ((row&7)<<4)).
// 3 blocks/CU co-resident (grid 768) overlap each other's barrier drains.
template <int KDIM>
__device__ __forceinline__ void gemm_core(const f16* __restrict__ A, const f16* __restrict__ Bt,
                                          int bm, int bn, f16* lA, f16* lB, f32x4 acc[4][4]) {
  const int t = threadIdx.x, lane = t & 63, wave = t >> 6;
  const int wm = wave >> 1, wn = wave & 1;
  const int srow = lane >> 3;            // row within 8-row chunk
  const int skb = (lane & 7) * 16;       // byte offset within 128B row
  const int nkt = KDIM / 64;
  for (int kt = 0; kt < nkt; ++kt) {
    __syncthreads();
#pragma unroll
    for (int c = 0; c < 4; ++c) {
      int cc = c * 4 + wave;             // 0..15, wave-uniform
      int row = cc * 8 + srow;           // 0..127
      int kbs = skb ^ ((row & 7) << 4);  // pre-swizzled source byte offset
      gload16((const char*)A + (size_t)(bm * 128 + row) * (KDIM * 2) + kt * 128 + kbs,
              lA + cc * 512);
      gload16((const char*)Bt + (size_t)(bn * 128 + row) * (KDIM * 2) + kt * 128 + kbs,
              lB + cc * 512);
    }
    __syncthreads();
#pragma unroll
    for (int ks = 0; ks < 2; ++ks) {
      f16x8 af[4], bf[4];
#pragma unroll
      for (int mi = 0; mi < 4; ++mi) {
        int r = wm * 64 + mi * 16 + (lane & 15);
        int ke = (ks * 32 + ((lane >> 4) << 3)) ^ ((r & 7) << 3);  // elements
        af[mi] = *(const f16x8*)&lA[r * 64 + ke];
      }
#pragma unroll
      for (int ni = 0; ni < 4; ++ni) {
        int r = wn * 64 + ni * 16 + (lane & 15);
        int ke = (ks * 32 + ((lane >> 4) << 3)) ^ ((r & 7) << 3);
        bf[ni] = *(const f16x8*)&lB[r * 64 + ke];
      }
#pragma unroll
      for (int mi = 0; mi < 4; ++mi)
#pragma unroll
        for (int ni = 0; ni < 4; ++ni)
          acc[mi][ni] = MFMA16(af[mi], bf[ni], acc[mi][ni]);
    }
  }
}

// ---------------- GEMM core 64x128 (R13/R18-verified) ----------------
// C[64x128] = A[bm*64.., K] * Bt[bn*128.., K]^T. 4 waves: wm = wave>>1 (32 rows),
// wn = wave&1 (64 cols); acc[2][4]. LDS 24KB -> 2+ blocks/CU.
template <int KDIM>
__device__ __forceinline__ void gemm_core64(const f16* __restrict__ A, const f16* __restrict__ Bt,
                                            int bm, int bn, f16* lA, f16* lB, f32x4 acc[2][4]) {
  const int t = threadIdx.x, lane = t & 63, wave = t >> 6;
  const int wm = wave >> 1, wn = wave & 1;
  const int srow = lane >> 3;            // row within 8-row chunk
  const int skb = (lane & 7) * 16;       // byte offset within 128B row
  const int nkt = KDIM / 64;
  for (int kt = 0; kt < nkt; ++kt) {
    __syncthreads();
#pragma unroll
    for (int c = 0; c < 2; ++c) {        // A: 8 chunks of 8 rows
      int cc = c * 4 + wave;             // 0..7
      int row = cc * 8 + srow;           // 0..63
      int kbs = skb ^ ((row & 7) << 4);
      gload16((const char*)A + (size_t)(bm * 64 + row) * (KDIM * 2) + kt * 128 + kbs,
              lA + cc * 512);
    }
#pragma unroll
    for (int c = 0; c < 4; ++c) {        // B: 16 chunks of 8 rows
      int cc = c * 4 + wave;             // 0..15
      int row = cc * 8 + srow;           // 0..127
      int kbs = skb ^ ((row & 7) << 4);
      gload16((const char*)Bt + (size_t)(bn * 128 + row) * (KDIM * 2) + kt * 128 + kbs,
              lB + cc * 512);
    }
    __syncthreads();
#pragma unroll
    for (int ks = 0; ks < 2; ++ks) {
      f16x8 af[2], bf[4];
#pragma unroll
      for (int mi = 0; mi < 2; ++mi) {
        int r = wm * 32 + mi * 16 + (lane & 15);
        int ke = (ks * 32 + ((lane >> 4) << 3)) ^ ((r & 7) << 3);
        af[mi] = *(const f16x8*)&lA[r * 64 + ke];
      }
#pragma unroll
      for (int ni = 0; ni < 4; ++ni) {
        int r = wn * 64 + ni * 16 + (lane & 15);
        int ke = (ks * 32 + ((lane >> 4) << 3)) ^ ((r & 7) << 3);
        bf[ni] = *(const f16x8*)&lB[r * 64 + ke];
      }
#pragma unroll
      for (int mi = 0; mi < 2; ++mi)
#pragma unroll
        for (int ni = 0; ni < 4; ++ni)
          acc[mi][ni] = MFMA16(af[mi], bf[ni], acc[mi][ni]);
    }
  }
}

// ---------------- QKV projection (R10-proven) ----------------
// A = x_f16 [4096,1024]; Bt = w_qkv^T [3072,1024].
// sec0 -> Q[B,H,N,D]*0.125*log2(e) ; sec1 -> K[B,H,N,D] ;
// sec2 -> V^T[B,H,D,N], key index permuted within 32-blocks so attention's PV
// B-fragment is lane-local; produced via LDS transpose -> f16x8 coalesced stores.
// Grid: 1D 768, XCD-chunked: XCD (w&7) owns an 8bm x 12bn tile chunk.
__global__ __launch_bounds__(256, 2) void gemm_qkv(const f16* __restrict__ A,
                                                   const f16* __restrict__ Bt,
                                                   f16* __restrict__ Qo, f16* __restrict__ Ko,
                                                   f16* __restrict__ Vt) {
  __shared__ __align__(16) f16 smem[128 * 136];  // 34816 B; staging uses first 32KB
  f16* lA = smem;
  f16* lB = smem + 8192;
  f32x4 acc[4][4] = {};
  int w = blockIdx.x;            // 0..767
  int xcd = w & 7, i = w >> 3;   // i in [0,96)
  int xr = xcd >> 1, xc = xcd & 1;
  int bm = xr * 8 + (i & 7);     // [0,32)
  int bn = xc * 12 + (i >> 3);   // [0,24)
  gemm_core<1024>(A, Bt, bm, bn, lA, lB, acc);
  int lane = threadIdx.x & 63, wave = threadIdx.x >> 6;
  int wm = wave >> 1, wn = wave & 1;
  int g = lane >> 4, q15 = lane & 15;
  int sec = (bn * 128) >> 10;  // 0=Q 1=K 2=V, uniform per block (128 | 1024)
  if (sec < 2) {
    float scl = (sec == 0) ? 0.18033688f : 1.0f;  // 0.125 * log2(e)
#pragma unroll
    for (int mi = 0; mi < 4; ++mi)
#pragma unroll
      for (int ni = 0; ni < 4; ++ni)
#pragma unroll
        for (int reg = 0; reg < 4; ++reg) {
          int gr = bm * 128 + wm * 64 + mi * 16 + (g << 2) + reg;  // [0,4096)
          int gc = bn * 128 + wn * 64 + ni * 16 + q15;             // [0,3072)
          int b = gr >> 11, n = gr & 2047;
          int jj = gc & 1023;
          int h = jj >> 6, d = jj & 63;
          f16 v = (f16)(acc[mi][ni][reg] * scl);
          size_t bh = (size_t)(b * 16 + h);
          if (sec == 0) Qo[(bh * 2048 + n) * 64 + d] = v;
          else          Ko[(bh * 2048 + n) * 64 + d] = v;
        }
  } else {
    // V: acc(rl = n, cl = head*64+d) -> LDS[cl][p(rl)] -> coalesced V^T
    __syncthreads();  // all LDS reads of the K-loop complete before overwrite
#pragma unroll
    for (int mi = 0; mi < 4; ++mi)
#pragma unroll
      for (int ni = 0; ni < 4; ++ni)
#pragma unroll
        for (int reg = 0; reg < 4; ++reg) {
          int rl = wm * 64 + mi * 16 + (g << 2) + reg;  // local n 0..127
          int cl = wn * 64 + ni * 16 + q15;             // local col 0..127
          int r5 = rl & 31;
          int rlp = (rl & ~31) | (((r5 >> 2) & 3) << 3) | (((r5 >> 4) & 1) << 2) | (r5 & 3);
          smem[cl * 136 + rlp] = (f16)acc[mi][ni][reg];
        }
    __syncthreads();
    int tid = threadIdx.x;
    int cl = tid >> 1, half = tid & 1;
    int jj = (bn * 128 + cl) & 1023;
    int h = jj >> 6, d = jj & 63;
    int b = (bm * 128) >> 11;
    size_t bh = (size_t)(b * 16 + h);
    f16* dst = Vt + (bh * 64 + d) * 2048 + (bm * 128 & 2047) + half * 64;
    const f16* src = smem + cl * 136 + half * 64;
#pragma unroll
    for (int j8 = 0; j8 < 8; ++j8)
      *(f16x8*)&dst[j8 * 8] = *(const f16x8*)&src[j8 * 8];
  }
}

// ---------------- causal flash attention (R11-best: 64-key, 4 blocks/CU) ----------------
// Q pre-scaled by 0.125*log2e (log2-domain scores). Q,K: [B,H,N,D] f16;
// Vt: [B,H,D,N] f16 (key-permuted); Ob: [N,C] slice.
// 64-key tiles, double-buffered with counted vmcnt (T4): 2 stages (4 loads each)
// in flight; WAITV(4) retires the stage being consumed while the newer 4 loads
// stay in flight across both barriers. K LDS [64][64], V LDS [64][64], row-swizzled.
// Swapped-operand: S^T = mfma(K, Q); q = lane&15, k = kv0 + 16*ni + 4*(lane>>4) + reg.
__device__ __forceinline__ void attn_one(const f16* __restrict__ Qb, const f16* __restrict__ Kb,
                                         const f16* __restrict__ Vb, f16* __restrict__ Ob,
                                         int qt, int lane, int wave, f16* lK, f16* lV) {
  const int N = 2048;
  const int wq0 = qt * 64 + wave * 16;
  const int g = lane >> 4, q15 = lane & 15;
  f16x8 qf[2];
#pragma unroll
  for (int ks = 0; ks < 2; ++ks)
    qf[ks] = *(const f16x8*)&Qb[(size_t)(wq0 + q15) * 64 + ks * 32 + (g << 3)];
  f32x4 oacc[4] = {};
  float mrun = -1e30f, lrun = 0.f;
  const int srow = lane >> 3, skb = (lane & 7) * 16;
  const int ntiles = qt + 1;  // 64-key tiles

  auto STAGE = [&](int buf, int kv) {  // 4 gload16 per wave
    int kv0 = kv << 6;
#pragma unroll
    for (int c = 0; c < 2; ++c) {
      int cc = c * 4 + wave;             // 0..7, wave-uniform
      int row = cc * 8 + srow;           // 0..63
      int kbs = skb ^ ((row & 7) << 4);  // pre-swizzled source
      gload16((const char*)Kb + (size_t)(kv0 + row) * 128 + kbs, lK + buf * 4096 + cc * 512);
      gload16((const char*)Vb + (size_t)row * (N * 2) + (size_t)kv0 * 2 + kbs,
              lV + buf * 4096 + cc * 512);
    }
  };

  STAGE(0, 0);
  if (ntiles > 1) STAGE(1, 1);
  for (int kv = 0; kv < ntiles; ++kv) {
    int cur = kv & 1;
    if (kv + 1 < ntiles) WAITV(4); else WAITV(0);
    BARRIER();  // buf cur complete in all waves
    const f16* K0 = lK + cur * 4096;
    const f16* V0 = lV + cur * 4096;
    int kv0 = kv << 6;
    f32x4 s[4] = {};
    __builtin_amdgcn_s_setprio(1);
#pragma unroll
    for (int ks = 0; ks < 2; ++ks) {
      f16x8 kf[4];
#pragma unroll
      for (int ni = 0; ni < 4; ++ni) {
        int r = ni * 16 + q15;                       // key row 0..63
        int ke = (ks * 32 + (g << 3)) ^ ((r & 7) << 3);
        kf[ni] = *(const f16x8*)&K0[r * 64 + ke];
      }
#pragma unroll
      for (int ni = 0; ni < 4; ++ni) s[ni] = MFMA16(kf[ni], qf[ks], s[ni]);  // S^T[k][q]
    }
    __builtin_amdgcn_s_setprio(0);
    if (kv == qt) {  // diagonal tile: causal mask. k = kv0+16ni+4g+reg, q = wq0+q15.
      int gq = wq0 + q15;
#pragma unroll
      for (int ni = 0; ni < 4; ++ni)
#pragma unroll
        for (int reg = 0; reg < 4; ++reg) {
          int gk = kv0 + ni * 16 + g * 4 + reg;
          if (gk > gq) s[ni][reg] = -1e30f;
        }
    }
    // per-lane max over 16 regs + 2 shfl (lanes l, l+16, l+32, l+48 share q)
    f32x4 m4 = s[0];
#pragma unroll
    for (int ni = 1; ni < 4; ++ni)
#pragma unroll
      for (int reg = 0; reg < 4; ++reg) m4[reg] = fmaxf(m4[reg], s[ni][reg]);
    float mx = fmaxf(fmaxf(m4[0], m4[1]), fmaxf(m4[2], m4[3]));
    mx = fmaxf(mx, __shfl_xor(mx, 16));
    mx = fmaxf(mx, __shfl_xor(mx, 32));
    // T13: rescale only if some row's running max grew (wave-uniform)
    if (__any(mx > mrun)) {
      float mnew = fmaxf(mrun, mx);
      float corr = ex2(mrun - mnew);
      mrun = mnew;
      lrun *= corr;
#pragma unroll
      for (int ni = 0; ni < 4; ++ni)
#pragma unroll
        for (int reg = 0; reg < 4; ++reg) oacc[ni][reg] *= corr;
    }
    // p = 2^(s-m); tree-shaped row-sum (4 parallel f32x4 chains + horizontal)
#pragma unroll
    for (int ni = 0; ni < 4; ++ni)
#pragma unroll
      for (int reg = 0; reg < 4; ++reg) s[ni][reg] = ex2(s[ni][reg] - mrun);
    f32x4 racc = (s[0] + s[1]) + (s[2] + s[3]);
    float rsum = (racc[0] + racc[1]) + (racc[2] + racc[3]);
    rsum += __shfl_xor(rsum, 16);
    rsum += __shfl_xor(rsum, 32);
    lrun += rsum;
    // pack P fragments (lane-local; order matches permuted V layout)
    f16x8 pf[2];
#pragma unroll
    for (int ks = 0; ks < 2; ++ks)
#pragma unroll
      for (int e = 0; e < 8; ++e) pf[ks][e] = (f16)s[2 * ks + (e >> 2)][e & 3];
    // O^T[d][q] += V^T_perm @ P  (A = V rows d from LDS, B = pf in-register)
    __builtin_amdgcn_s_setprio(1);
#pragma unroll
    for (int ks = 0; ks < 2; ++ks) {
      f16x8 vf[4];
#pragma unroll
      for (int mi = 0; mi < 4; ++mi) {
        int r = mi * 16 + q15;                       // d row 0..63
        int ke = (ks * 32 + (g << 3)) ^ ((r & 7) << 3);
        vf[mi] = *(const f16x8*)&V0[r * 64 + ke];
      }
#pragma unroll
      for (int mi = 0; mi < 4; ++mi) oacc[mi] = MFMA16(vf[mi], pf[ks], oacc[mi]);
    }
    __builtin_amdgcn_s_setprio(0);
    BARRIER();  // all waves done reading cur
    CFENCE();
    if (kv + 2 < ntiles) STAGE(cur, kv + 2);
  }
  // epilogue: O^T[d][q] -> Ob[q, d]; d = 16*mi + 4*g + reg (4 contiguous per mi)
  float inv = 1.0f / lrun;
  int gq = wq0 + q15;
#pragma unroll
  for (int mi = 0; mi < 4; ++mi) {
    f16x4 o4;
#pragma unroll
    for (int reg = 0; reg < 4; ++reg) o4[reg] = (f16)(oacc[mi][reg] * inv);
    *(f16x4*)&Ob[(size_t)gq * 1024 + mi * 16 + g * 4] = o4;
  }
}

// 1024 blocks, one 64-row q-tile each -> 4 blocks/CU.
// XCD-chunked (T1): XCD c = w&7 owns heads [4c,4c+4) -> 2 MB K/V set per XCD L2.
// Sum-uniform placement: within a chunk, j = 32a + k; under breadth-first
// dispatch CU k receives a=0..3 with qt {k, 31-k, (k+8)&31, 31-((k+8)&31)}
// -> per-CU work sums to exactly 66 tile-units for every k.
__global__ __launch_bounds__(256, 4) void attn(const f16* __restrict__ Q,
                                               const f16* __restrict__ K,
                                               const f16* __restrict__ Vt,
                                               f16* __restrict__ O) {
  __shared__ __align__(16) f16 lK[2 * 4096];
  __shared__ __align__(16) f16 lV[2 * 4096];
  int w = blockIdx.x;             // 0..1023
  int c = w & 7, j = w >> 3;      // XCD chunk id, index within chunk [0,128)
  int a = j >> 5, k = j & 31;     // head-slot, CU-slot
  int bh = c * 4 + a;
  int kk = (a >= 2) ? ((k + 8) & 31) : k;
  int qt = (a & 1) ? (31 - kk) : kk;
  int b = bh >> 4, h = bh & 15;
  int lane = threadIdx.x & 63, wave = threadIdx.x >> 6;
  const f16* Qb = Q + (size_t)bh * 2048 * 64;
  const f16* Kb = K + (size_t)bh * 2048 * 64;
  const f16* Vb = Vt + (size_t)bh * 2048 * 64;
  f16* Ob = O + (size_t)b * 2048 * 1024 + h * 64;
  attn_one(Qb, Kb, Vb, Ob, qt, lane, wave, lK, lV);
}

// ---------------- output projection: 64x128 tiles, 512 blocks (2/CU) ----------------
// Splitting M (not N) keeps B-panel traffic small (B is only 1024 wide); the
// second co-resident block overlaps the other's barrier drains.
// XCD-chunked: XCD (w&7) owns 8bm x 8bn.
__global__ __launch_bounds__(256, 2) void gemm_out(const f16* __restrict__ A,
                                                   const f16* __restrict__ Bt,
                                                   const float* __restrict__ bias,
                                                   float* __restrict__ out) {
  __shared__ __align__(16) f16 smem[12288];  // 24KB: lA 8KB + lB 16KB
  f16* lA = smem;
  f16* lB = smem + 4096;
  f32x4 acc[2][4] = {};
  int w = blockIdx.x;           // 0..511
  int xcd = w & 7, i = w >> 3;  // [0,64)
  int bm = xcd * 8 + (i & 7);   // [0,64)
  int bn = i >> 3;              // [0,8)
  gemm_core64<1024>(A, Bt, bm, bn, lA, lB, acc);
  int lane = threadIdx.x & 63, wave = threadIdx.x >> 6;
  int wm = wave >> 1, wn = wave & 1;
#pragma unroll
  for (int mi = 0; mi < 2; ++mi)
#pragma unroll
    for (int ni = 0; ni < 4; ++ni)
#pragma unroll
      for (int reg = 0; reg < 4; ++reg) {
        int gr = bm * 64 + wm * 32 + mi * 16 + ((lane >> 4) << 2) + reg;
        int gc = bn * 128 + wn * 64 + ni * 16 + (lane & 15);
        out[(size_t)gr * 1024 + gc] = acc[mi][ni][reg] + bias[gc];
      }
}

// ---------------- launcher ----------------
extern "C" void kernel_launch(void* const* d_in, const int* in_sizes, int n_in,
                              void* d_out, int out_size, void* d_ws, size_t ws_size,
                              hipStream_t stream) {
  const float* x     = (const float*)d_in[0];  // [2,2048,1024]
  const float* w_qkv = (const float*)d_in[1];  // [1024,3072]
  const float* w_out = (const float*)d_in[2];  // [1024,1024]
  const float* b_out = (const float*)d_in[3];  // [1024]
  // d_in[4] = attn_mask (causal; computed analytically)
  float* out = (float*)d_out;
  char* ws = (char*)d_ws;

  f16* xh    = (f16*)(ws);                   //  8 MB [4096,1024]
  f16* wqkvT = (f16*)(ws + (8u << 20));      //  6 MB [3072,1024]
  f16* woutT = (f16*)(ws + (14u << 20));     //  2 MB [1024,1024]
  f16* Qs    = (f16*)(ws + (16u << 20));     //  8 MB [B,H,N,D] (pre-scaled, log2-domain)
  f16* Ks    = (f16*)(ws + (24u << 20));     //  8 MB [B,H,N,D]
  f16* Vts   = (f16*)(ws + (32u << 20));     //  8 MB [B,H,D,N] (key-permuted)
  f16* Oa    = (f16*)(ws + (40u << 20));     //  8 MB [B,N,H*D]

  prep<<<4096 + 128 * 32, 256, 0, stream>>>(x, xh, w_qkv, wqkvT, w_out, woutT);
  gemm_qkv<<<768, 256, 0, stream>>>(xh, wqkvT, Qs, Ks, Vts);
  attn<<<1024, 256, 0, stream>>>(Qs, Ks, Vts, Oa);
  gemm_out<<<512, 256, 0, stream>>>(Oa, woutT, b_out, out);
}